// Round 16
// baseline (78.368 us; speedup 1.0000x reference)
//
#include <hip/hip_runtime.h>
#include <math.h>

#define HID 64
#define BKT_SHIFT 13                 // 8192 nodes per bucket
#define BKT_RANGE 8192
#define CCHUNK 32                    // wave-chunks per bucket in phase B

typedef __attribute__((ext_vector_type(8))) short short8;
typedef __attribute__((ext_vector_type(4))) float f32x4;
typedef unsigned long long ull;

union FragU {
    uint4 q;
    short8 v;
    uint32_t u[4];
};

__device__ __forceinline__ uint32_t cvt_pk_bf16(float lo, float hi) {
    uint32_t r;
    asm("v_cvt_pk_bf16_f32 %0, %1, %2" : "=v"(r) : "v"(lo), "v"(hi));
    return r;
}

// ---------------------------------------------------------------------------
// Edge v11: DUAL-BATCH interleave (T15 pattern). Each block processes two
// independent 256-edge batches (A = bi, B = bi+grid) per iteration, phase-
// interleaved: L1(A,2sets) ; L1(B,2sets) ; gathers ; L2(A) ; L2(B) ; x2
// phases through 2x 2-set tiles (32 KB total). Doubles independent work
// between every lgkm-latency dependency (shfl -> MFMA -> LDS -> MFMA chain)
// at the same occupancy. Tail (accum/node) reverted to round-13 exact.
// ---------------------------------------------------------------------------
__global__ __launch_bounds__(256, 2) void edge_dual_kernel(
    const float* __restrict__ nf, const float* __restrict__ ef,
    const int* __restrict__ src, const int* __restrict__ dst,
    const float* __restrict__ w1, const float* __restrict__ b1,
    const float* __restrict__ w2, const float* __restrict__ b2,
    const float* __restrict__ w3, const float* __restrict__ b3,
    uint2* __restrict__ recs, ull* __restrict__ offs,
    float* __restrict__ aggFb, int E, int B, int nbatch, int mode)
{
    __shared__ uint2 tile[4][2][2][16][16];   // [wave][batch][set-in-phase][row][chunk] = 32 KB

    const int tid  = threadIdx.x;
    const int lane = tid & 63;
    const int wid  = tid >> 6;
    const int g    = lane >> 4;
    const int eL   = lane & 15;

    // ---- self-build weight fragments (once per block) ----
    FragU af1[4];
#pragma unroll
    for (int t = 0; t < 4; ++t) {
        int j = t * 16 + eL;
        uint32_t u0 = cvt_pk_bf16(w1[j], w1[HID + j]);
        uint32_t u1 = cvt_pk_bf16(w1[2 * HID + j], b1[j]);
        af1[t].u[0] = (g == 0) ? u0 : 0u;
        af1[t].u[1] = (g == 0) ? u1 : 0u;
        af1[t].u[2] = 0u; af1[t].u[3] = 0u;
    }
    FragU af2[4][2];
#pragma unroll
    for (int t = 0; t < 4; ++t)
#pragma unroll
        for (int h = 0; h < 2; ++h)
#pragma unroll
            for (int e2 = 0; e2 < 4; ++e2) {
                int k0 = h * 32 + g * 8 + 2 * e2;
                int j  = t * 16 + eL;
                af2[t][h].u[e2] = cvt_pk_bf16(w2[k0 * HID + j], w2[(k0 + 1) * HID + j]);
            }
    f32x4 b2v4[4], w3v4[4];
#pragma unroll
    for (int t = 0; t < 4; ++t) {
        int j = t * 16 + g * 4;
        b2v4[t] = *(const f32x4*)&b2[j];
        w3v4[t] = *(const f32x4*)&w3[j];
    }
    const float b3c = b3[0];

    // ---- lambdas: one L1 set, one L2 set, record append ----
    auto L1SET = [&](uint32_t ab, uint32_t c1, int s, uint2 (*tl)[16]) {
        int sel = s * 16 + eL;
        uint32_t u0 = (uint32_t)__shfl((int)ab, sel);
        uint32_t u1 = (uint32_t)__shfl((int)c1, sel);
        FragU bin;
        bin.u[0] = (g == 0) ? u0 : 0u;
        bin.u[1] = (g == 0) ? u1 : 0u;
        bin.u[2] = 0u; bin.u[3] = 0u;
#pragma unroll
        for (int t = 0; t < 4; ++t) {
            f32x4 h4 = __builtin_amdgcn_mfma_f32_16x16x32_bf16(
                af1[t].v, bin.v, (f32x4){0.f, 0.f, 0.f, 0.f}, 0, 0, 0);
            uint32_t p0 = cvt_pk_bf16(fmaxf(h4[0], 0.f), fmaxf(h4[1], 0.f));
            uint32_t p1 = cvt_pk_bf16(fmaxf(h4[2], 0.f), fmaxf(h4[3], 0.f));
            tl[eL][(4 * t + g) ^ ((eL & 7) << 1)] = make_uint2(p0, p1);
        }
    };
    auto L2SET = [&](uint2 (*tl)[16]) -> float {
        const uint4* row = (const uint4*)&tl[eL][0];
        FragU bf0, bf1;
        bf0.q = row[(g)     ^ (eL & 7)];
        bf1.q = row[(4 + g) ^ (eL & 7)];
        float q0, q1, q2, q3;
        {
            f32x4 ac = __builtin_amdgcn_mfma_f32_16x16x32_bf16(af2[0][0].v, bf0.v, b2v4[0], 0, 0, 0);
            ac = __builtin_amdgcn_mfma_f32_16x16x32_bf16(af2[0][1].v, bf1.v, ac, 0, 0, 0);
            q0 = fmaxf(ac[0], 0.f) * w3v4[0][0];
            q0 = fmaf(fmaxf(ac[1], 0.f), w3v4[0][1], q0);
            q0 = fmaf(fmaxf(ac[2], 0.f), w3v4[0][2], q0);
            q0 = fmaf(fmaxf(ac[3], 0.f), w3v4[0][3], q0);
        }
        {
            f32x4 ac = __builtin_amdgcn_mfma_f32_16x16x32_bf16(af2[1][0].v, bf0.v, b2v4[1], 0, 0, 0);
            ac = __builtin_amdgcn_mfma_f32_16x16x32_bf16(af2[1][1].v, bf1.v, ac, 0, 0, 0);
            q1 = fmaxf(ac[0], 0.f) * w3v4[1][0];
            q1 = fmaf(fmaxf(ac[1], 0.f), w3v4[1][1], q1);
            q1 = fmaf(fmaxf(ac[2], 0.f), w3v4[1][2], q1);
            q1 = fmaf(fmaxf(ac[3], 0.f), w3v4[1][3], q1);
        }
        {
            f32x4 ac = __builtin_amdgcn_mfma_f32_16x16x32_bf16(af2[2][0].v, bf0.v, b2v4[2], 0, 0, 0);
            ac = __builtin_amdgcn_mfma_f32_16x16x32_bf16(af2[2][1].v, bf1.v, ac, 0, 0, 0);
            q2 = fmaxf(ac[0], 0.f) * w3v4[2][0];
            q2 = fmaf(fmaxf(ac[1], 0.f), w3v4[2][1], q2);
            q2 = fmaf(fmaxf(ac[2], 0.f), w3v4[2][2], q2);
            q2 = fmaf(fmaxf(ac[3], 0.f), w3v4[2][3], q2);
        }
        {
            f32x4 ac = __builtin_amdgcn_mfma_f32_16x16x32_bf16(af2[3][0].v, bf0.v, b2v4[3], 0, 0, 0);
            ac = __builtin_amdgcn_mfma_f32_16x16x32_bf16(af2[3][1].v, bf1.v, ac, 0, 0, 0);
            q3 = fmaxf(ac[0], 0.f) * w3v4[3][0];
            q3 = fmaf(fmaxf(ac[1], 0.f), w3v4[3][1], q3);
            q3 = fmaf(fmaxf(ac[2], 0.f), w3v4[3][2], q3);
            q3 = fmaf(fmaxf(ac[3], 0.f), w3v4[3][3], q3);
        }
        float p = (q0 + q1) + (q2 + q3);
        p += __shfl_xor(p, 16);
        p += __shfl_xor(p, 32);
        return p;
    };
    auto APPEND = [&](int bb_i, int eix, int dc, float msg) {
        const bool valid = eix < E;
        const int bkt = dc >> BKT_SHIFT;
        const ull lt = (1ull << lane) - 1;
        int myslot = 0;
        int off = 0;
        uint32_t plo = 0, phi = 0;
        for (int bb = 0; bb < B; ++bb) {
            if (bb < 4) plo |= (uint32_t)off << (8 * bb);
            else        phi |= (uint32_t)off << (8 * (bb - 4));
            ull m = __ballot(valid && bkt == bb);
            if (valid && bkt == bb) myslot = off + (int)__popcll(m & lt);
            off += (int)__popcll(m);
        }
        phi |= (uint32_t)off << 24;
        const size_t wgl = (size_t)bb_i * 4 + wid;
        if (valid) recs[wgl * 64 + myslot] = make_uint2((uint32_t)dc, __float_as_uint(msg));
        if (lane == 0) offs[wgl] = ((ull)phi << 32) | (ull)plo;
    };

    const int gsz = gridDim.x;
    int biA = blockIdx.x;
    if (biA >= nbatch) return;

    // ---- initial loads: batch A and B ----
    int eixA = biA * 256 + tid;
    int eiA  = eixA < E ? eixA : E - 1;
    int dcA  = dst[eiA];
    float aA = nf[src[eiA]];
    float bA = nf[dcA];
    float cA = ef[eiA];
    uint32_t abA = cvt_pk_bf16(aA, bA);
    uint32_t c1A = cvt_pk_bf16(cA, 1.0f);

    int  biB  = biA + gsz;
    bool hasB = biB < nbatch;
    int eixB = hasB ? biB * 256 + tid : eixA;
    int eiB  = eixB < E ? eixB : E - 1;
    int dcB  = dst[eiB];
    float aB = nf[src[eiB]];
    float bB = nf[dcB];
    float cB = ef[eiB];
    uint32_t abB = cvt_pk_bf16(aB, bB);
    uint32_t c1B = cvt_pk_bf16(cB, 1.0f);

    for (;;) {
        // ---- prefetch next pair indices ----
        const int  nbiA = biA + 2 * gsz;
        const bool hnA  = nbiA < nbatch;
        const int  neixA = hnA ? nbiA * 256 + tid : eixA;
        const int  neiA  = neixA < E ? neixA : E - 1;
        const int  nsA = src[neiA];
        const int  ndA = dst[neiA];
        const float ncA = ef[neiA];

        const int  nbiB = nbiA + gsz;
        const bool hnB  = nbiB < nbatch;
        const int  neixB = hnB ? nbiB * 256 + tid : eixA;
        const int  neiB  = neixB < E ? neixB : E - 1;
        const int  nsB = src[neiB];
        const int  ndB = dst[neiB];
        const float ncB = ef[neiB];

        float naA = 0.f, nbA2 = 0.f, naB = 0.f, nbB2 = 0.f;
        float msgA = 0.f, msgB = 0.f;

#pragma unroll
        for (int ph = 0; ph < 2; ++ph) {
            // L1 phase: sets 2ph, 2ph+1 for BOTH batches (independent streams)
#pragma unroll
            for (int ss = 0; ss < 2; ++ss) {
                const int s = 2 * ph + ss;
                L1SET(abA, c1A, s, tile[wid][0][ss]);
                L1SET(abB, c1B, s, tile[wid][1][ss]);
            }
            if (ph == 0) {
                naA  = nf[nsA];
                nbA2 = nf[ndA];
                naB  = nf[nsB];
                nbB2 = nf[ndB];
            }
            // L2 phase: both batches
#pragma unroll
            for (int ss = 0; ss < 2; ++ss) {
                const int s = 2 * ph + ss;
                float pA = L2SET(tile[wid][0][ss]);
                if (s == g) msgA = pA + b3c;
                float pB = L2SET(tile[wid][1][ss]);
                if (s == g) msgB = pB + b3c;
            }
        }

        if (mode == 1) {
            if (eixA < E) atomicAdd(&aggFb[dcA], msgA);
            if (hasB && eixB < E) atomicAdd(&aggFb[dcB], msgB);
        } else {
            APPEND(biA, eixA, dcA, msgA);
            if (hasB) APPEND(biB, eixB, dcB, msgB);
        }

        if (!hnA) break;
        biA = nbiA; eixA = neixA; dcA = ndA;
        abA = cvt_pk_bf16(naA, nbA2);
        c1A = cvt_pk_bf16(ncA, 1.0f);
        biB = nbiB; hasB = hnB; eixB = neixB; dcB = ndB;
        abB = cvt_pk_bf16(naB, nbB2);
        c1B = cvt_pk_bf16(ncB, 1.0f);
    }
}

// ---------------------------------------------------------------------------
// Phase B (round-13 exact): block (b,c) accumulates bucket b's records from
// wave-chunk c into a 32KB LDS plane (LDS atomics). Block 0 zeroes rd + ctr.
// ---------------------------------------------------------------------------
__global__ __launch_bounds__(256) void bucket_accum_kernel(
    const uint2* __restrict__ recs, const ull* __restrict__ offs,
    float* __restrict__ partial, float* __restrict__ rd, unsigned* __restrict__ ctr,
    int G, int NW, int B)
{
    __shared__ float acc[BKT_RANGE];

    const int b = blockIdx.x / CCHUNK;
    const int c = blockIdx.x % CCHUNK;

    if (blockIdx.x == 0) {
        for (int i = threadIdx.x; i < G; i += 256) rd[i] = 0.f;
        if (threadIdx.x == 0) *ctr = 0u;
    }

    for (int i = threadIdx.x; i < BKT_RANGE; i += 256) acc[i] = 0.f;
    __syncthreads();

    const int wpc = (NW + CCHUNK - 1) / CCHUNK;
    const int w0 = c * wpc;
    const int w1 = (w0 + wpc < NW) ? w0 + wpc : NW;
    const int nb = b + 1;
    const int base_node = b << BKT_SHIFT;

    for (int w = w0 + threadIdx.x; w < w1; w += 256) {
        ull ov = offs[w];
        uint32_t lo = (uint32_t)ov, hi = (uint32_t)(ov >> 32);
        int ob = (int)(((b  < 4) ? (lo >> (8 * b))  : (hi >> (8 * (b  - 4)))) & 0xFF);
        int oe = (int)(((nb < 4) ? (lo >> (8 * nb)) : (hi >> (8 * (nb - 4)))) & 0xFF);
        const uint2* rb = recs + (size_t)w * 64;
        for (int r = ob; r < oe; ++r) {
            uint2 rec = rb[r];
            atomicAdd(&acc[(int)rec.x - base_node], __uint_as_float(rec.y));
        }
    }
    __syncthreads();

    float* pb = partial + ((size_t)b * CCHUNK + c) * BKT_RANGE;
    for (int i = threadIdx.x; i < BKT_RANGE; i += 256) pb[i] = acc[i];
}

// ---------------------------------------------------------------------------
// Node v5 (round-13 exact): 4-wave blocks, 64 nodes/wave, both MLPs on MFMA,
// self-built fragments, fused plane-reduce and last-block readout.
// ---------------------------------------------------------------------------
__global__ __launch_bounds__(256, 2) void node_mfma5_kernel(
    const float* __restrict__ nf, const float* __restrict__ partial,
    const float* __restrict__ aggFb, int nplanes,
    const int* __restrict__ gid,
    const float* __restrict__ nw1, const float* __restrict__ nb1,
    const float* __restrict__ nw2, const float* __restrict__ nb2,
    const float* __restrict__ nw3, const float* __restrict__ nb3,
    const float* __restrict__ mw1, const float* __restrict__ mb1,
    const float* __restrict__ mw2, const float* __restrict__ mb2,
    const float* __restrict__ mw3, const float* __restrict__ mb3,
    float* __restrict__ rd, float* __restrict__ outp, unsigned* __restrict__ ctr,
    int N, int G)
{
    __shared__ uint2 tile[4][4][16][16];   // 32 KB
    __shared__ int lastflag;

    const int tid  = threadIdx.x;
    const int lane = tid & 63;
    const int wid  = tid >> 6;
    const int g    = lane >> 4;
    const int eL   = lane & 15;

    const int idx = blockIdx.x * 256 + tid;
    const int i   = idx < N ? idx : N - 1;
    const float x0 = nf[i];
    const int   gg = gid[i];

    float x1;
    if (nplanes == 1) {
        x1 = aggFb[i];
    } else {
        int bb = i >> BKT_SHIFT, nl = i & (BKT_RANGE - 1);
        const float* p = partial + (size_t)bb * CCHUNK * BKT_RANGE + nl;
        x1 = 0.f;
#pragma unroll 8
        for (int c = 0; c < CCHUNK; ++c) x1 += p[(size_t)c * BKT_RANGE];
    }

    float myunf = 0.f, o = 0.f;

    // ================= MLP-N: [nf, agg] -> unf =================
    {
        FragU af1[4], af2[4][2];
        f32x4 b2v4[4], w3v4[4];
#pragma unroll
        for (int t = 0; t < 4; ++t) {
            int j = t * 16 + eL;
            uint32_t u0 = cvt_pk_bf16(nw1[j], nw1[HID + j]);
            uint32_t u1 = cvt_pk_bf16(nb1[j], 0.f);
            af1[t].u[0] = (g == 0) ? u0 : 0u;
            af1[t].u[1] = (g == 0) ? u1 : 0u;
            af1[t].u[2] = 0u; af1[t].u[3] = 0u;
#pragma unroll
            for (int h = 0; h < 2; ++h)
#pragma unroll
                for (int e2 = 0; e2 < 4; ++e2) {
                    int k0 = h * 32 + g * 8 + 2 * e2;
                    af2[t][h].u[e2] = cvt_pk_bf16(nw2[k0 * HID + j], nw2[(k0 + 1) * HID + j]);
                }
            int j4 = t * 16 + g * 4;
            b2v4[t] = *(const f32x4*)&nb2[j4];
            w3v4[t] = *(const f32x4*)&nw3[j4];
        }
        uint32_t pk01 = cvt_pk_bf16(x0, x1);
        uint32_t pkb  = cvt_pk_bf16(1.0f, 0.f);

#pragma unroll
        for (int s = 0; s < 4; ++s) {
            int sel = s * 16 + eL;
            uint32_t u0 = (uint32_t)__shfl((int)pk01, sel);
            FragU bin;
            bin.u[0] = (g == 0) ? u0 : 0u;
            bin.u[1] = (g == 0) ? pkb : 0u;
            bin.u[2] = 0u; bin.u[3] = 0u;
#pragma unroll
            for (int t = 0; t < 4; ++t) {
                f32x4 h4 = __builtin_amdgcn_mfma_f32_16x16x32_bf16(
                    af1[t].v, bin.v, (f32x4){0.f, 0.f, 0.f, 0.f}, 0, 0, 0);
                uint32_t p0 = cvt_pk_bf16(fmaxf(h4[0], 0.f), fmaxf(h4[1], 0.f));
                uint32_t p1 = cvt_pk_bf16(fmaxf(h4[2], 0.f), fmaxf(h4[3], 0.f));
                tile[wid][s][eL][(4 * t + g) ^ ((eL & 7) << 1)] = make_uint2(p0, p1);
            }
        }
#pragma unroll
        for (int s = 0; s < 4; ++s) {
            const uint4* row = (const uint4*)&tile[wid][s][eL][0];
            FragU bf0, bf1;
            bf0.q = row[(g)     ^ (eL & 7)];
            bf1.q = row[(4 + g) ^ (eL & 7)];
            float p = 0.f;
#pragma unroll
            for (int t = 0; t < 4; ++t) {
                f32x4 ac = __builtin_amdgcn_mfma_f32_16x16x32_bf16(af2[t][0].v, bf0.v, b2v4[t], 0, 0, 0);
                ac = __builtin_amdgcn_mfma_f32_16x16x32_bf16(af2[t][1].v, bf1.v, ac, 0, 0, 0);
                p = fmaf(fmaxf(ac[0], 0.f), w3v4[t][0], p);
                p = fmaf(fmaxf(ac[1], 0.f), w3v4[t][1], p);
                p = fmaf(fmaxf(ac[2], 0.f), w3v4[t][2], p);
                p = fmaf(fmaxf(ac[3], 0.f), w3v4[t][3], p);
            }
            p += __shfl_xor(p, 16);
            p += __shfl_xor(p, 32);
            if (s == g) myunf = p + nb3[0];
        }
    }

    // ================= MLP-M: unf -> o =================
    {
        FragU af1[4], af2[4][2];
        f32x4 b2v4[4], w3v4[4];
#pragma unroll
        for (int t = 0; t < 4; ++t) {
            int j = t * 16 + eL;
            uint32_t u0 = cvt_pk_bf16(mw1[j], mb1[j]);
            af1[t].u[0] = (g == 0) ? u0 : 0u;
            af1[t].u[1] = 0u; af1[t].u[2] = 0u; af1[t].u[3] = 0u;
#pragma unroll
            for (int h = 0; h < 2; ++h)
#pragma unroll
                for (int e2 = 0; e2 < 4; ++e2) {
                    int k0 = h * 32 + g * 8 + 2 * e2;
                    af2[t][h].u[e2] = cvt_pk_bf16(mw2[k0 * HID + j], mw2[(k0 + 1) * HID + j]);
                }
            int j4 = t * 16 + g * 4;
            b2v4[t] = *(const f32x4*)&mb2[j4];
            w3v4[t] = *(const f32x4*)&mw3[j4];
        }

#pragma unroll
        for (int s = 0; s < 4; ++s) {
            float uv = __shfl(myunf, s * 16 + eL);
            FragU bin;
            bin.u[0] = (g == 0) ? cvt_pk_bf16(uv, 1.0f) : 0u;
            bin.u[1] = 0u; bin.u[2] = 0u; bin.u[3] = 0u;
#pragma unroll
            for (int t = 0; t < 4; ++t) {
                f32x4 h4 = __builtin_amdgcn_mfma_f32_16x16x32_bf16(
                    af1[t].v, bin.v, (f32x4){0.f, 0.f, 0.f, 0.f}, 0, 0, 0);
                uint32_t p0 = cvt_pk_bf16(fmaxf(h4[0], 0.f), fmaxf(h4[1], 0.f));
                uint32_t p1 = cvt_pk_bf16(fmaxf(h4[2], 0.f), fmaxf(h4[3], 0.f));
                tile[wid][s][eL][(4 * t + g) ^ ((eL & 7) << 1)] = make_uint2(p0, p1);
            }
        }
#pragma unroll
        for (int s = 0; s < 4; ++s) {
            const uint4* row = (const uint4*)&tile[wid][s][eL][0];
            FragU bf0, bf1;
            bf0.q = row[(g)     ^ (eL & 7)];
            bf1.q = row[(4 + g) ^ (eL & 7)];
            float p = 0.f;
#pragma unroll
            for (int t = 0; t < 4; ++t) {
                f32x4 ac = __builtin_amdgcn_mfma_f32_16x16x32_bf16(af2[t][0].v, bf0.v, b2v4[t], 0, 0, 0);
                ac = __builtin_amdgcn_mfma_f32_16x16x32_bf16(af2[t][1].v, bf1.v, ac, 0, 0, 0);
                p = fmaf(fmaxf(ac[0], 0.f), w3v4[t][0], p);
                p = fmaf(fmaxf(ac[1], 0.f), w3v4[t][1], p);
                p = fmaf(fmaxf(ac[2], 0.f), w3v4[t][2], p);
                p = fmaf(fmaxf(ac[3], 0.f), w3v4[t][3], p);
            }
            p += __shfl_xor(p, 16);
            p += __shfl_xor(p, 32);
            if (s == g) o = p + mb3[0];
        }
    }

    const float node_out = 1.0f / (1.0f + expf(-o));

    // ---- segmented reduction over sorted gid, one atomic per run tail ----
    {
        const bool ok = idx < N;
        float v = ok ? node_out : 0.0f;
        int ggv = gg;
#pragma unroll
        for (int d = 1; d < 64; d <<= 1) {
            float vup = __shfl_up(v, d);
            int   gup = __shfl_up(ggv, d);
            if (lane >= d && gup == ggv) v += vup;
        }
        int gdn = __shfl_down(ggv, 1);
        bool tail = (lane == 63) || (gdn != ggv);
        if (tail)
            atomicAdd(&rd[ggv], v);
    }

    // ---- fused readout: last block applies sigmoid(rd) -> out ----
    if (ctr) {
        if (tid == 0) {
            __threadfence();
            unsigned v = atomicAdd(ctr, 1u);
            lastflag = (v == (unsigned)(gridDim.x - 1)) ? 1 : 0;
        }
        __syncthreads();
        if (lastflag) {
            __threadfence();
            for (int q = tid; q < G; q += 256)
                outp[q] = 1.0f / (1.0f + expf(-rd[q]));
        }
    }
}

__global__ void readout_kernel(const float* __restrict__ rd,
                               float* __restrict__ out, int G)
{
    int g = blockIdx.x * blockDim.x + threadIdx.x;
    if (g < G) out[g] = 1.0f / (1.0f + expf(-rd[g]));
}

extern "C" void kernel_launch(void* const* d_in, const int* in_sizes, int n_in,
                              void* d_out, int out_size, void* d_ws, size_t ws_size,
                              hipStream_t stream)
{
    const float* nf  = (const float*)d_in[0];
    const float* ef  = (const float*)d_in[1];
    const int*   src = (const int*)  d_in[2];
    const int*   dst = (const int*)  d_in[3];
    const int*   gid = (const int*)  d_in[4];

    const float* e_w1 = (const float*)d_in[5];
    const float* e_b1 = (const float*)d_in[6];
    const float* e_w2 = (const float*)d_in[7];
    const float* e_b2 = (const float*)d_in[8];
    const float* e_w3 = (const float*)d_in[9];
    const float* e_b3 = (const float*)d_in[10];

    const float* n_w1 = (const float*)d_in[11];
    const float* n_b1 = (const float*)d_in[12];
    const float* n_w2 = (const float*)d_in[13];
    const float* n_b2 = (const float*)d_in[14];
    const float* n_w3 = (const float*)d_in[15];
    const float* n_b3 = (const float*)d_in[16];

    const float* m_w1 = (const float*)d_in[17];
    const float* m_b1 = (const float*)d_in[18];
    const float* m_w2 = (const float*)d_in[19];
    const float* m_b2 = (const float*)d_in[20];
    const float* m_w3 = (const float*)d_in[21];
    const float* m_b3 = (const float*)d_in[22];

    const int N = in_sizes[0];   // 50000
    const int E = in_sizes[2];   // 1600000
    const int G = out_size;      // 512

    const int nbatch = (E + 255) / 256;
    const int NW = (E + 63) / 64;
    const int B  = (N + BKT_RANGE - 1) / BKT_RANGE;

    size_t recs_b = (size_t)NW * 64 * sizeof(uint2);
    size_t offs_b = (size_t)NW * sizeof(ull);
    size_t part_b = (size_t)B * CCHUNK * BKT_RANGE * sizeof(float);
    size_t need   = recs_b + offs_b + part_b + (size_t)G * sizeof(float) + 64;
    bool bucketok = (B <= 8) && (need <= ws_size);

    char* wp = (char*)d_ws;
    float* out = (float*)d_out;

    int egrid = nbatch < 1024 ? nbatch : 1024;

    if (bucketok) {
        uint2*    recs    = (uint2*)wp;
        ull*      offs    = (ull*)(wp + recs_b);
        float*    partial = (float*)(wp + recs_b + offs_b);
        float*    rd      = (float*)(wp + recs_b + offs_b + part_b);
        unsigned* ctr     = (unsigned*)(wp + recs_b + offs_b + part_b + (size_t)G * sizeof(float));

        edge_dual_kernel<<<egrid, 256, 0, stream>>>(
            nf, ef, src, dst, e_w1, e_b1, e_w2, e_b2, e_w3, e_b3,
            recs, offs, nullptr, E, B, nbatch, 0);

        bucket_accum_kernel<<<B * CCHUNK, 256, 0, stream>>>(
            recs, offs, partial, rd, ctr, G, NW, B);

        node_mfma5_kernel<<<(N + 255) / 256, 256, 0, stream>>>(
            nf, partial, nullptr, CCHUNK, gid,
            n_w1, n_b1, n_w2, n_b2, n_w3, n_b3,
            m_w1, m_b1, m_w2, m_b2, m_w3, m_b3,
            rd, out, ctr, N, G);
    } else {
        float* agg = (float*)wp;
        float* rd  = agg + N;

        hipMemsetAsync(agg, 0, ((size_t)N + G) * sizeof(float), stream);

        edge_dual_kernel<<<egrid, 256, 0, stream>>>(
            nf, ef, src, dst, e_w1, e_b1, e_w2, e_b2, e_w3, e_b3,
            nullptr, nullptr, agg, E, B, nbatch, 1);

        node_mfma5_kernel<<<(N + 255) / 256, 256, 0, stream>>>(
            nf, nullptr, agg, 1, gid,
            n_w1, n_b1, n_w2, n_b2, n_w3, n_b3,
            m_w1, m_b1, m_w2, m_b2, m_w3, m_b3,
            rd, out, nullptr, N, G);

        readout_kernel<<<(G + 255) / 256, 256, 0, stream>>>(rd, out, G);
    }
}

// Round 17
// 71.749 us; speedup vs baseline: 1.0923x; 1.0923x over previous
//
#include <hip/hip_runtime.h>
#include <math.h>

#define HID 64
#define BKT_SHIFT 13                 // 8192 nodes per bucket
#define BKT_RANGE 8192
#define CCHUNK 32                    // wave-chunks per bucket in phase B

typedef __attribute__((ext_vector_type(8))) short short8;
typedef __attribute__((ext_vector_type(4))) float f32x4;
typedef unsigned long long ull;

union FragU {
    uint4 q;
    short8 v;
    uint32_t u[4];
};

__device__ __forceinline__ uint32_t cvt_pk_bf16(float lo, float hi) {
    uint32_t r;
    asm("v_cvt_pk_bf16_f32 %0, %1, %2" : "=v"(r) : "v"(lo), "v"(hi));
    return r;
}

// ---------------------------------------------------------------------------
// Edge v9 (round-13 exact, session optimum ~42.5 us): persistent grid 1024,
// L1x4 -> L2x4, 32 KB tile, self-built bf16 fragments from raw f32 weights,
// packed-input shfl, ballot/popc bucket-grouped coalesced record append.
// ---------------------------------------------------------------------------
__global__ __launch_bounds__(256, 2) void edge_mfma8_kernel(
    const float* __restrict__ nf, const float* __restrict__ ef,
    const int* __restrict__ src, const int* __restrict__ dst,
    const float* __restrict__ w1, const float* __restrict__ b1,
    const float* __restrict__ w2, const float* __restrict__ b2,
    const float* __restrict__ w3, const float* __restrict__ b3,
    uint2* __restrict__ recs, ull* __restrict__ offs,
    float* __restrict__ aggFb, int E, int B, int nbatch, int mode)
{
    __shared__ uint2 tile[4][4][16][16];   // 32 KB

    const int tid  = threadIdx.x;
    const int lane = tid & 63;
    const int wid  = tid >> 6;
    const int g    = lane >> 4;
    const int eL   = lane & 15;

    // ---- self-build weight fragments (once per block) ----
    FragU af1[4];
#pragma unroll
    for (int t = 0; t < 4; ++t) {
        int j = t * 16 + eL;
        uint32_t u0 = cvt_pk_bf16(w1[j], w1[HID + j]);
        uint32_t u1 = cvt_pk_bf16(w1[2 * HID + j], b1[j]);
        af1[t].u[0] = (g == 0) ? u0 : 0u;
        af1[t].u[1] = (g == 0) ? u1 : 0u;
        af1[t].u[2] = 0u; af1[t].u[3] = 0u;
    }
    FragU af2[4][2];
#pragma unroll
    for (int t = 0; t < 4; ++t)
#pragma unroll
        for (int h = 0; h < 2; ++h)
#pragma unroll
            for (int e2 = 0; e2 < 4; ++e2) {
                int k0 = h * 32 + g * 8 + 2 * e2;
                int j  = t * 16 + eL;
                af2[t][h].u[e2] = cvt_pk_bf16(w2[k0 * HID + j], w2[(k0 + 1) * HID + j]);
            }
    f32x4 b2v4[4], w3v4[4];
#pragma unroll
    for (int t = 0; t < 4; ++t) {
        int j = t * 16 + g * 4;
        b2v4[t] = *(const f32x4*)&b2[j];
        w3v4[t] = *(const f32x4*)&w3[j];
    }
    const float b3c = b3[0];

    // ---- first batch ----
    int bi   = blockIdx.x;
    if (bi >= nbatch) return;
    int eidx = bi * 256 + tid;
    int ei   = eidx < E ? eidx : E - 1;
    int dcur = dst[ei];
    float a  = nf[src[ei]];
    float b  = nf[dcur];
    float c  = ef[ei];
    uint32_t pkab = cvt_pk_bf16(a, b);
    uint32_t pkc1 = cvt_pk_bf16(c, 1.0f);

    for (;;) {
        // ---- prefetch next batch indices ----
        const int nbi   = bi + gridDim.x;
        const bool hn   = nbi < nbatch;
        const int neidx = hn ? nbi * 256 + tid : eidx;
        const int nei   = neidx < E ? neidx : E - 1;
        const int ns    = src[nei];
        const int nd    = dst[nei];
        const float ncf = ef[nei];

        // ---- L1 phase: 4 sets, 16 independent MFMAs ----
#pragma unroll
        for (int s = 0; s < 4; ++s) {
            int sel = s * 16 + eL;
            uint32_t u0 = (uint32_t)__shfl((int)pkab, sel);
            uint32_t u1 = (uint32_t)__shfl((int)pkc1, sel);
            FragU bin;
            bin.u[0] = (g == 0) ? u0 : 0u;
            bin.u[1] = (g == 0) ? u1 : 0u;
            bin.u[2] = 0u; bin.u[3] = 0u;
#pragma unroll
            for (int t = 0; t < 4; ++t) {
                f32x4 h4 = __builtin_amdgcn_mfma_f32_16x16x32_bf16(
                    af1[t].v, bin.v, (f32x4){0.f, 0.f, 0.f, 0.f}, 0, 0, 0);
                uint32_t p0 = cvt_pk_bf16(fmaxf(h4[0], 0.f), fmaxf(h4[1], 0.f));
                uint32_t p1 = cvt_pk_bf16(fmaxf(h4[2], 0.f), fmaxf(h4[3], 0.f));
                tile[wid][s][eL][(4 * t + g) ^ ((eL & 7) << 1)] = make_uint2(p0, p1);
            }
        }

        // ---- next batch gathers (hidden under L2 phase) ----
        const float na = nf[ns];
        const float nb = nf[nd];

        // ---- L2 phase: 4 sets x 8 MFMAs + epilogue (4 indep chains) ----
        float mymsg = 0.f;
#pragma unroll
        for (int s = 0; s < 4; ++s) {
            const uint4* row = (const uint4*)&tile[wid][s][eL][0];
            FragU bf0, bf1;
            bf0.q = row[(g)     ^ (eL & 7)];
            bf1.q = row[(4 + g) ^ (eL & 7)];

            float q0, q1, q2, q3;
            {
                f32x4 ac = __builtin_amdgcn_mfma_f32_16x16x32_bf16(af2[0][0].v, bf0.v, b2v4[0], 0, 0, 0);
                ac = __builtin_amdgcn_mfma_f32_16x16x32_bf16(af2[0][1].v, bf1.v, ac, 0, 0, 0);
                q0 = fmaxf(ac[0], 0.f) * w3v4[0][0];
                q0 = fmaf(fmaxf(ac[1], 0.f), w3v4[0][1], q0);
                q0 = fmaf(fmaxf(ac[2], 0.f), w3v4[0][2], q0);
                q0 = fmaf(fmaxf(ac[3], 0.f), w3v4[0][3], q0);
            }
            {
                f32x4 ac = __builtin_amdgcn_mfma_f32_16x16x32_bf16(af2[1][0].v, bf0.v, b2v4[1], 0, 0, 0);
                ac = __builtin_amdgcn_mfma_f32_16x16x32_bf16(af2[1][1].v, bf1.v, ac, 0, 0, 0);
                q1 = fmaxf(ac[0], 0.f) * w3v4[1][0];
                q1 = fmaf(fmaxf(ac[1], 0.f), w3v4[1][1], q1);
                q1 = fmaf(fmaxf(ac[2], 0.f), w3v4[1][2], q1);
                q1 = fmaf(fmaxf(ac[3], 0.f), w3v4[1][3], q1);
            }
            {
                f32x4 ac = __builtin_amdgcn_mfma_f32_16x16x32_bf16(af2[2][0].v, bf0.v, b2v4[2], 0, 0, 0);
                ac = __builtin_amdgcn_mfma_f32_16x16x32_bf16(af2[2][1].v, bf1.v, ac, 0, 0, 0);
                q2 = fmaxf(ac[0], 0.f) * w3v4[2][0];
                q2 = fmaf(fmaxf(ac[1], 0.f), w3v4[2][1], q2);
                q2 = fmaf(fmaxf(ac[2], 0.f), w3v4[2][2], q2);
                q2 = fmaf(fmaxf(ac[3], 0.f), w3v4[2][3], q2);
            }
            {
                f32x4 ac = __builtin_amdgcn_mfma_f32_16x16x32_bf16(af2[3][0].v, bf0.v, b2v4[3], 0, 0, 0);
                ac = __builtin_amdgcn_mfma_f32_16x16x32_bf16(af2[3][1].v, bf1.v, ac, 0, 0, 0);
                q3 = fmaxf(ac[0], 0.f) * w3v4[3][0];
                q3 = fmaf(fmaxf(ac[1], 0.f), w3v4[3][1], q3);
                q3 = fmaf(fmaxf(ac[2], 0.f), w3v4[3][2], q3);
                q3 = fmaf(fmaxf(ac[3], 0.f), w3v4[3][3], q3);
            }
            float p = (q0 + q1) + (q2 + q3);
            p += __shfl_xor(p, 16);
            p += __shfl_xor(p, 32);
            if (s == g) mymsg = p + b3c;
        }

        const bool valid = eidx < E;

        if (mode == 1) {
            if (valid) atomicAdd(&aggFb[dcur], mymsg);
        } else {
            // ---- bucket append: coalesced wave-private, zero atomics ----
            const int bkt = dcur >> BKT_SHIFT;
            const ull lt = (1ull << lane) - 1;
            int myslot = 0;
            int off = 0;
            uint32_t pack_lo = 0, pack_hi = 0;
            for (int bb = 0; bb < B; ++bb) {
                if (bb < 4) pack_lo |= (uint32_t)off << (8 * bb);
                else        pack_hi |= (uint32_t)off << (8 * (bb - 4));
                ull m = __ballot(valid && bkt == bb);
                if (valid && bkt == bb) myslot = off + (int)__popcll(m & lt);
                off += (int)__popcll(m);
            }
            pack_hi |= (uint32_t)off << 24;

            const size_t wgl = (size_t)bi * 4 + wid;
            if (valid) recs[wgl * 64 + myslot] = make_uint2((uint32_t)dcur, __float_as_uint(mymsg));
            if (lane == 0) offs[wgl] = ((ull)pack_hi << 32) | (ull)pack_lo;
        }

        if (!hn) break;
        bi = nbi; eidx = neidx;
        pkab = cvt_pk_bf16(na, nb);
        pkc1 = cvt_pk_bf16(ncf, 1.0f);
        dcur = nd;
    }
}

// ---------------------------------------------------------------------------
// Phase B (round-13 exact): block (b,c) accumulates bucket b's records from
// wave-chunk c into a 32KB LDS plane (LDS atomics). Block 0 zeroes rd + ctr.
// ---------------------------------------------------------------------------
__global__ __launch_bounds__(256) void bucket_accum_kernel(
    const uint2* __restrict__ recs, const ull* __restrict__ offs,
    float* __restrict__ partial, float* __restrict__ rd, unsigned* __restrict__ ctr,
    int G, int NW, int B)
{
    __shared__ float acc[BKT_RANGE];

    const int b = blockIdx.x / CCHUNK;
    const int c = blockIdx.x % CCHUNK;

    if (blockIdx.x == 0) {
        for (int i = threadIdx.x; i < G; i += 256) rd[i] = 0.f;
        if (threadIdx.x == 0) *ctr = 0u;
    }

    for (int i = threadIdx.x; i < BKT_RANGE; i += 256) acc[i] = 0.f;
    __syncthreads();

    const int wpc = (NW + CCHUNK - 1) / CCHUNK;
    const int w0 = c * wpc;
    const int w1 = (w0 + wpc < NW) ? w0 + wpc : NW;
    const int nb = b + 1;
    const int base_node = b << BKT_SHIFT;

    for (int w = w0 + threadIdx.x; w < w1; w += 256) {
        ull ov = offs[w];
        uint32_t lo = (uint32_t)ov, hi = (uint32_t)(ov >> 32);
        int ob = (int)(((b  < 4) ? (lo >> (8 * b))  : (hi >> (8 * (b  - 4)))) & 0xFF);
        int oe = (int)(((nb < 4) ? (lo >> (8 * nb)) : (hi >> (8 * (nb - 4)))) & 0xFF);
        const uint2* rb = recs + (size_t)w * 64;
        for (int r = ob; r < oe; ++r) {
            uint2 rec = rb[r];
            atomicAdd(&acc[(int)rec.x - base_node], __uint_as_float(rec.y));
        }
    }
    __syncthreads();

    float* pb = partial + ((size_t)b * CCHUNK + c) * BKT_RANGE;
    for (int i = threadIdx.x; i < BKT_RANGE; i += 256) pb[i] = acc[i];
}

// ---------------------------------------------------------------------------
// Node v5 (round-13 exact): 4-wave blocks, 64 nodes/wave, both MLPs on MFMA,
// self-built fragments, fused plane-reduce and last-block readout.
// ---------------------------------------------------------------------------
__global__ __launch_bounds__(256, 2) void node_mfma5_kernel(
    const float* __restrict__ nf, const float* __restrict__ partial,
    const float* __restrict__ aggFb, int nplanes,
    const int* __restrict__ gid,
    const float* __restrict__ nw1, const float* __restrict__ nb1,
    const float* __restrict__ nw2, const float* __restrict__ nb2,
    const float* __restrict__ nw3, const float* __restrict__ nb3,
    const float* __restrict__ mw1, const float* __restrict__ mb1,
    const float* __restrict__ mw2, const float* __restrict__ mb2,
    const float* __restrict__ mw3, const float* __restrict__ mb3,
    float* __restrict__ rd, float* __restrict__ outp, unsigned* __restrict__ ctr,
    int N, int G)
{
    __shared__ uint2 tile[4][4][16][16];   // 32 KB
    __shared__ int lastflag;

    const int tid  = threadIdx.x;
    const int lane = tid & 63;
    const int wid  = tid >> 6;
    const int g    = lane >> 4;
    const int eL   = lane & 15;

    const int idx = blockIdx.x * 256 + tid;
    const int i   = idx < N ? idx : N - 1;
    const float x0 = nf[i];
    const int   gg = gid[i];

    float x1;
    if (nplanes == 1) {
        x1 = aggFb[i];
    } else {
        int bb = i >> BKT_SHIFT, nl = i & (BKT_RANGE - 1);
        const float* p = partial + (size_t)bb * CCHUNK * BKT_RANGE + nl;
        x1 = 0.f;
#pragma unroll 8
        for (int c = 0; c < CCHUNK; ++c) x1 += p[(size_t)c * BKT_RANGE];
    }

    float myunf = 0.f, o = 0.f;

    // ================= MLP-N: [nf, agg] -> unf =================
    {
        FragU af1[4], af2[4][2];
        f32x4 b2v4[4], w3v4[4];
#pragma unroll
        for (int t = 0; t < 4; ++t) {
            int j = t * 16 + eL;
            uint32_t u0 = cvt_pk_bf16(nw1[j], nw1[HID + j]);
            uint32_t u1 = cvt_pk_bf16(nb1[j], 0.f);
            af1[t].u[0] = (g == 0) ? u0 : 0u;
            af1[t].u[1] = (g == 0) ? u1 : 0u;
            af1[t].u[2] = 0u; af1[t].u[3] = 0u;
#pragma unroll
            for (int h = 0; h < 2; ++h)
#pragma unroll
                for (int e2 = 0; e2 < 4; ++e2) {
                    int k0 = h * 32 + g * 8 + 2 * e2;
                    af2[t][h].u[e2] = cvt_pk_bf16(nw2[k0 * HID + j], nw2[(k0 + 1) * HID + j]);
                }
            int j4 = t * 16 + g * 4;
            b2v4[t] = *(const f32x4*)&nb2[j4];
            w3v4[t] = *(const f32x4*)&nw3[j4];
        }
        uint32_t pk01 = cvt_pk_bf16(x0, x1);
        uint32_t pkb  = cvt_pk_bf16(1.0f, 0.f);

#pragma unroll
        for (int s = 0; s < 4; ++s) {
            int sel = s * 16 + eL;
            uint32_t u0 = (uint32_t)__shfl((int)pk01, sel);
            FragU bin;
            bin.u[0] = (g == 0) ? u0 : 0u;
            bin.u[1] = (g == 0) ? pkb : 0u;
            bin.u[2] = 0u; bin.u[3] = 0u;
#pragma unroll
            for (int t = 0; t < 4; ++t) {
                f32x4 h4 = __builtin_amdgcn_mfma_f32_16x16x32_bf16(
                    af1[t].v, bin.v, (f32x4){0.f, 0.f, 0.f, 0.f}, 0, 0, 0);
                uint32_t p0 = cvt_pk_bf16(fmaxf(h4[0], 0.f), fmaxf(h4[1], 0.f));
                uint32_t p1 = cvt_pk_bf16(fmaxf(h4[2], 0.f), fmaxf(h4[3], 0.f));
                tile[wid][s][eL][(4 * t + g) ^ ((eL & 7) << 1)] = make_uint2(p0, p1);
            }
        }
#pragma unroll
        for (int s = 0; s < 4; ++s) {
            const uint4* row = (const uint4*)&tile[wid][s][eL][0];
            FragU bf0, bf1;
            bf0.q = row[(g)     ^ (eL & 7)];
            bf1.q = row[(4 + g) ^ (eL & 7)];
            float p = 0.f;
#pragma unroll
            for (int t = 0; t < 4; ++t) {
                f32x4 ac = __builtin_amdgcn_mfma_f32_16x16x32_bf16(af2[t][0].v, bf0.v, b2v4[t], 0, 0, 0);
                ac = __builtin_amdgcn_mfma_f32_16x16x32_bf16(af2[t][1].v, bf1.v, ac, 0, 0, 0);
                p = fmaf(fmaxf(ac[0], 0.f), w3v4[t][0], p);
                p = fmaf(fmaxf(ac[1], 0.f), w3v4[t][1], p);
                p = fmaf(fmaxf(ac[2], 0.f), w3v4[t][2], p);
                p = fmaf(fmaxf(ac[3], 0.f), w3v4[t][3], p);
            }
            p += __shfl_xor(p, 16);
            p += __shfl_xor(p, 32);
            if (s == g) myunf = p + nb3[0];
        }
    }

    // ================= MLP-M: unf -> o =================
    {
        FragU af1[4], af2[4][2];
        f32x4 b2v4[4], w3v4[4];
#pragma unroll
        for (int t = 0; t < 4; ++t) {
            int j = t * 16 + eL;
            uint32_t u0 = cvt_pk_bf16(mw1[j], mb1[j]);
            af1[t].u[0] = (g == 0) ? u0 : 0u;
            af1[t].u[1] = 0u; af1[t].u[2] = 0u; af1[t].u[3] = 0u;
#pragma unroll
            for (int h = 0; h < 2; ++h)
#pragma unroll
                for (int e2 = 0; e2 < 4; ++e2) {
                    int k0 = h * 32 + g * 8 + 2 * e2;
                    af2[t][h].u[e2] = cvt_pk_bf16(mw2[k0 * HID + j], mw2[(k0 + 1) * HID + j]);
                }
            int j4 = t * 16 + g * 4;
            b2v4[t] = *(const f32x4*)&mb2[j4];
            w3v4[t] = *(const f32x4*)&mw3[j4];
        }

#pragma unroll
        for (int s = 0; s < 4; ++s) {
            float uv = __shfl(myunf, s * 16 + eL);
            FragU bin;
            bin.u[0] = (g == 0) ? cvt_pk_bf16(uv, 1.0f) : 0u;
            bin.u[1] = 0u; bin.u[2] = 0u; bin.u[3] = 0u;
#pragma unroll
            for (int t = 0; t < 4; ++t) {
                f32x4 h4 = __builtin_amdgcn_mfma_f32_16x16x32_bf16(
                    af1[t].v, bin.v, (f32x4){0.f, 0.f, 0.f, 0.f}, 0, 0, 0);
                uint32_t p0 = cvt_pk_bf16(fmaxf(h4[0], 0.f), fmaxf(h4[1], 0.f));
                uint32_t p1 = cvt_pk_bf16(fmaxf(h4[2], 0.f), fmaxf(h4[3], 0.f));
                tile[wid][s][eL][(4 * t + g) ^ ((eL & 7) << 1)] = make_uint2(p0, p1);
            }
        }
#pragma unroll
        for (int s = 0; s < 4; ++s) {
            const uint4* row = (const uint4*)&tile[wid][s][eL][0];
            FragU bf0, bf1;
            bf0.q = row[(g)     ^ (eL & 7)];
            bf1.q = row[(4 + g) ^ (eL & 7)];
            float p = 0.f;
#pragma unroll
            for (int t = 0; t < 4; ++t) {
                f32x4 ac = __builtin_amdgcn_mfma_f32_16x16x32_bf16(af2[t][0].v, bf0.v, b2v4[t], 0, 0, 0);
                ac = __builtin_amdgcn_mfma_f32_16x16x32_bf16(af2[t][1].v, bf1.v, ac, 0, 0, 0);
                p = fmaf(fmaxf(ac[0], 0.f), w3v4[t][0], p);
                p = fmaf(fmaxf(ac[1], 0.f), w3v4[t][1], p);
                p = fmaf(fmaxf(ac[2], 0.f), w3v4[t][2], p);
                p = fmaf(fmaxf(ac[3], 0.f), w3v4[t][3], p);
            }
            p += __shfl_xor(p, 16);
            p += __shfl_xor(p, 32);
            if (s == g) o = p + mb3[0];
        }
    }

    const float node_out = 1.0f / (1.0f + expf(-o));

    // ---- segmented reduction over sorted gid, one atomic per run tail ----
    {
        const bool ok = idx < N;
        float v = ok ? node_out : 0.0f;
        int ggv = gg;
#pragma unroll
        for (int d = 1; d < 64; d <<= 1) {
            float vup = __shfl_up(v, d);
            int   gup = __shfl_up(ggv, d);
            if (lane >= d && gup == ggv) v += vup;
        }
        int gdn = __shfl_down(ggv, 1);
        bool tail = (lane == 63) || (gdn != ggv);
        if (tail)
            atomicAdd(&rd[ggv], v);
    }

    // ---- fused readout: last block applies sigmoid(rd) -> out ----
    if (ctr) {
        if (tid == 0) {
            __threadfence();
            unsigned v = atomicAdd(ctr, 1u);
            lastflag = (v == (unsigned)(gridDim.x - 1)) ? 1 : 0;
        }
        __syncthreads();
        if (lastflag) {
            __threadfence();
            for (int q = tid; q < G; q += 256)
                outp[q] = 1.0f / (1.0f + expf(-rd[q]));
        }
    }
}

__global__ void readout_kernel(const float* __restrict__ rd,
                               float* __restrict__ out, int G)
{
    int g = blockIdx.x * blockDim.x + threadIdx.x;
    if (g < G) out[g] = 1.0f / (1.0f + expf(-rd[g]));
}

extern "C" void kernel_launch(void* const* d_in, const int* in_sizes, int n_in,
                              void* d_out, int out_size, void* d_ws, size_t ws_size,
                              hipStream_t stream)
{
    const float* nf  = (const float*)d_in[0];
    const float* ef  = (const float*)d_in[1];
    const int*   src = (const int*)  d_in[2];
    const int*   dst = (const int*)  d_in[3];
    const int*   gid = (const int*)  d_in[4];

    const float* e_w1 = (const float*)d_in[5];
    const float* e_b1 = (const float*)d_in[6];
    const float* e_w2 = (const float*)d_in[7];
    const float* e_b2 = (const float*)d_in[8];
    const float* e_w3 = (const float*)d_in[9];
    const float* e_b3 = (const float*)d_in[10];

    const float* n_w1 = (const float*)d_in[11];
    const float* n_b1 = (const float*)d_in[12];
    const float* n_w2 = (const float*)d_in[13];
    const float* n_b2 = (const float*)d_in[14];
    const float* n_w3 = (const float*)d_in[15];
    const float* n_b3 = (const float*)d_in[16];

    const float* m_w1 = (const float*)d_in[17];
    const float* m_b1 = (const float*)d_in[18];
    const float* m_w2 = (const float*)d_in[19];
    const float* m_b2 = (const float*)d_in[20];
    const float* m_w3 = (const float*)d_in[21];
    const float* m_b3 = (const float*)d_in[22];

    const int N = in_sizes[0];   // 50000
    const int E = in_sizes[2];   // 1600000
    const int G = out_size;      // 512

    const int nbatch = (E + 255) / 256;
    const int NW = (E + 63) / 64;
    const int B  = (N + BKT_RANGE - 1) / BKT_RANGE;

    size_t recs_b = (size_t)NW * 64 * sizeof(uint2);
    size_t offs_b = (size_t)NW * sizeof(ull);
    size_t part_b = (size_t)B * CCHUNK * BKT_RANGE * sizeof(float);
    size_t need   = recs_b + offs_b + part_b + (size_t)G * sizeof(float) + 64;
    bool bucketok = (B <= 8) && (need <= ws_size);

    char* wp = (char*)d_ws;
    float* out = (float*)d_out;

    int egrid = nbatch < 1024 ? nbatch : 1024;

    if (bucketok) {
        uint2*    recs    = (uint2*)wp;
        ull*      offs    = (ull*)(wp + recs_b);
        float*    partial = (float*)(wp + recs_b + offs_b);
        float*    rd      = (float*)(wp + recs_b + offs_b + part_b);
        unsigned* ctr     = (unsigned*)(wp + recs_b + offs_b + part_b + (size_t)G * sizeof(float));

        edge_mfma8_kernel<<<egrid, 256, 0, stream>>>(
            nf, ef, src, dst, e_w1, e_b1, e_w2, e_b2, e_w3, e_b3,
            recs, offs, nullptr, E, B, nbatch, 0);

        bucket_accum_kernel<<<B * CCHUNK, 256, 0, stream>>>(
            recs, offs, partial, rd, ctr, G, NW, B);

        node_mfma5_kernel<<<(N + 255) / 256, 256, 0, stream>>>(
            nf, partial, nullptr, CCHUNK, gid,
            n_w1, n_b1, n_w2, n_b2, n_w3, n_b3,
            m_w1, m_b1, m_w2, m_b2, m_w3, m_b3,
            rd, out, ctr, N, G);
    } else {
        float* agg = (float*)wp;
        float* rd  = agg + N;

        hipMemsetAsync(agg, 0, ((size_t)N + G) * sizeof(float), stream);

        edge_mfma8_kernel<<<egrid, 256, 0, stream>>>(
            nf, ef, src, dst, e_w1, e_b1, e_w2, e_b2, e_w3, e_b3,
            nullptr, nullptr, agg, E, B, nbatch, 1);

        node_mfma5_kernel<<<(N + 255) / 256, 256, 0, stream>>>(
            nf, nullptr, agg, 1, gid,
            n_w1, n_b1, n_w2, n_b2, n_w3, n_b3,
            m_w1, m_b1, m_w2, m_b2, m_w3, m_b3,
            rd, out, nullptr, N, G);

        readout_kernel<<<(G + 255) / 256, 256, 0, stream>>>(rd, out, G);
    }
}